// Round 3
// 209.388 us; speedup vs baseline: 1.0247x; 1.0247x over previous
//
#include <hip/hip_runtime.h>
#include <hip/hip_bf16.h>

// Problem constants (B=2, P=2048, D=768, H=12, hd=64)
#define B_  2
#define P_  2048
#define D_  768
#define H_  12
#define HD_ 64
#define M_  (B_ * P_)   // 4096
#define N1_ (3 * D_)    // 2304

typedef __attribute__((ext_vector_type(8))) short short8;    // 8 bf16 (4 VGPRs)
typedef __attribute__((ext_vector_type(4))) float f32x4;     // 16x16 MFMA acc
typedef __attribute__((ext_vector_type(16))) float f32x16;   // 32x32 MFMA acc
typedef __attribute__((ext_vector_type(4))) unsigned u32x4;
typedef unsigned short ushort;

__device__ __forceinline__ ushort f2bf(float f) {
    unsigned u = __float_as_uint(f);
    u += 0x7fffu + ((u >> 16) & 1u);   // RNE
    return (ushort)(u >> 16);
}

// Pack two floats into one dword of 2x bf16 (lo = a, hi = b), RNE.
__device__ __forceinline__ unsigned pk2bf(float a, float b) {
    return (unsigned)f2bf(a) | ((unsigned)f2bf(b) << 16);
}

// Swap bits 2 and 3 of a slot index (involution). Staging K rows at slot
// swap23(kr) makes the 32x32 MFMA C-layout's half-interleaved row order come
// out as the exact PV B-fragment element order — no cross-lane exchange.
__device__ __forceinline__ int swap23(int s) {
    return (s & ~12) | ((s & 4) << 1) | ((s & 8) >> 1);
}

// ===========================================================================
// Kernel 1: qkv = x @ W_qkv (bf16 MFMA) + fused per-head QK-LayerNorm.
// 128x128 tile, BK=32, 512 threads / 8 waves (4x2). (unchanged)
// ===========================================================================
__global__ __launch_bounds__(512) void gemm_qkv_mfma(
        const float* __restrict__ x, const float* __restrict__ w,
        const float* __restrict__ qs, const float* __restrict__ qb,
        const float* __restrict__ ks, const float* __restrict__ kb,
        ushort* __restrict__ qkv) {
    __shared__ __align__(16) ushort As[128][40];
    __shared__ __align__(16) ushort Bs[128][40];

    const int tid  = threadIdx.x;
    const int lane = tid & 63;
    const int wv   = tid >> 6;            // 0..7
    const int quad = lane >> 4;
    const int col  = lane & 15;
    const int wr   = (wv >> 1) * 32;
    const int wc   = (wv & 1) * 64;
    const int rowBase = blockIdx.y * 128;
    const int colBase = blockIdx.x * 128;

    const int am0 = tid >> 3, ac4 = tid & 7;
    const int nB  = tid & 127, kq = tid >> 7;

    float4 apre[2];
    float  bpre[8];
    auto load_tile = [&](int kt) {
        const int k0 = kt * 32;
        apre[0] = *(const float4*)(x + (size_t)(rowBase + am0) * D_ + k0 + ac4 * 4);
        apre[1] = *(const float4*)(x + (size_t)(rowBase + am0 + 64) * D_ + k0 + ac4 * 4);
#pragma unroll
        for (int j = 0; j < 8; j++)
            bpre[j] = w[(size_t)(k0 + kq * 8 + j) * N1_ + colBase + nB];
    };

    f32x4 acc[2][4];
#pragma unroll
    for (int i = 0; i < 2; i++)
#pragma unroll
        for (int j = 0; j < 4; j++) acc[i][j] = (f32x4){0.f, 0.f, 0.f, 0.f};

    load_tile(0);
    const int NT = D_ / 32;
    for (int kt = 0; kt < NT; kt++) {
        __syncthreads();
        {
            ushort u0[4] = {f2bf(apre[0].x), f2bf(apre[0].y), f2bf(apre[0].z), f2bf(apre[0].w)};
            ushort u1[4] = {f2bf(apre[1].x), f2bf(apre[1].y), f2bf(apre[1].z), f2bf(apre[1].w)};
            *(uint2*)&As[am0][ac4 * 4]      = *(uint2*)u0;
            *(uint2*)&As[am0 + 64][ac4 * 4] = *(uint2*)u1;
            ushort us[8];
#pragma unroll
            for (int j = 0; j < 8; j++) us[j] = f2bf(bpre[j]);
            *(short8*)&Bs[nB][kq * 8] = *(short8*)&us[0];
        }
        __syncthreads();
        if (kt + 1 < NT) load_tile(kt + 1);

        short8 af[2], bf[4];
#pragma unroll
        for (int mt = 0; mt < 2; mt++) af[mt] = *(const short8*)&As[wr + mt * 16 + col][quad * 8];
#pragma unroll
        for (int nt = 0; nt < 4; nt++) bf[nt] = *(const short8*)&Bs[wc + nt * 16 + col][quad * 8];
#pragma unroll
        for (int mt = 0; mt < 2; mt++)
#pragma unroll
            for (int nt = 0; nt < 4; nt++)
                acc[mt][nt] = __builtin_amdgcn_mfma_f32_16x16x32_bf16(af[mt], bf[nt], acc[mt][nt], 0, 0, 0);
    }

    const int comp = colBase / D_;
    const int rem  = colBase + wc - comp * D_;
    const int h    = rem >> 6;
    float sc4[4] = {0, 0, 0, 0}, bi4[4] = {0, 0, 0, 0};
    if (comp == 0) {
#pragma unroll
        for (int nt = 0; nt < 4; nt++) { sc4[nt] = qs[nt * 16 + col]; bi4[nt] = qb[nt * 16 + col]; }
    } else if (comp == 1) {
#pragma unroll
        for (int nt = 0; nt < 4; nt++) { sc4[nt] = ks[nt * 16 + col]; bi4[nt] = kb[nt * 16 + col]; }
    }

#pragma unroll
    for (int mt = 0; mt < 2; mt++) {
#pragma unroll
        for (int r = 0; r < 4; r++) {
            int m  = rowBase + wr + mt * 16 + quad * 4 + r;
            int bb = m >> 11;
            int p  = m & 2047;
            float v0 = acc[mt][0][r], v1 = acc[mt][1][r], v2 = acc[mt][2][r], v3 = acc[mt][3][r];
            if (comp < 2) {
                float s = v0 + v1 + v2 + v3;
#pragma unroll
                for (int off = 1; off < 16; off <<= 1) s += __shfl_xor(s, off, 64);
                float mean = s * (1.0f / 64.0f);
                float d0 = v0 - mean, d1 = v1 - mean, d2 = v2 - mean, d3 = v3 - mean;
                float sq = d0 * d0 + d1 * d1 + d2 * d2 + d3 * d3;
#pragma unroll
                for (int off = 1; off < 16; off <<= 1) sq += __shfl_xor(sq, off, 64);
                float inv = rsqrtf(sq * (1.0f / 64.0f) + 1e-6f);
                v0 = d0 * inv * sc4[0] + bi4[0];
                v1 = d1 * inv * sc4[1] + bi4[1];
                v2 = d2 * inv * sc4[2] + bi4[2];
                v3 = d3 * inv * sc4[3] + bi4[3];
                if (comp == 0) { v0 *= 0.125f; v1 *= 0.125f; v2 *= 0.125f; v3 *= 0.125f; }
            }
            size_t base = ((((size_t)comp * B_ + bb) * H_ + h) * P_ + p) * HD_;
            qkv[base +  0 + col] = f2bf(v0);
            qkv[base + 16 + col] = f2bf(v1);
            qkv[base + 32 + col] = f2bf(v2);
            qkv[base + 48 + col] = f2bf(v3);
        }
    }
}

// ===========================================================================
// Kernel 2: flash attention, swapped-operand QK^T; P^T PV-fragments built
// entirely in-register via the K-slot bit2<->bit3 staging permutation.
// Block = 128 q rows, 4 waves; wave owns 32 q. Split-K over gridDim.z.
//
// S^T = mfma(A=K, B=Q): C col = q = lane&31, row = key SLOT =
//   (reg&3)+8*(reg>>2)+4*half. K row kr is staged at slot swap23(kr), so
//   slot s holds global key swap23(s). Element j of PV's B-frag (needs key
//   kp2*16+8h+j) = p[kp2*8+j], whose slot is 16kp2+8(j>>2)+4h+(j&3) ->
//   global key 16kp2+8h+4(j>>2)+(j&3) = kp2*16+8h+j.  (no cross-lane ops)
// O^T = mfma(A=V^T from Vs[dim][key] linear, B=P^T).
// Softmax sums are slot-permutation invariant. No P LDS buffer.
// ===========================================================================
__global__ __launch_bounds__(256) void attn_split(const ushort* __restrict__ qkv,
                                                  float* __restrict__ o0, float* __restrict__ o1,
                                                  float* __restrict__ o2, float* __restrict__ o3,
                                                  float* __restrict__ l0, float* __restrict__ l1,
                                                  float* __restrict__ l2, float* __restrict__ l3) {
    const int p0  = blockIdx.x * 128;
    const int bh  = blockIdx.y;
    const int s   = blockIdx.z;
    const int nsp = gridDim.z;           // 2 or 4
    const int b   = bh / H_, h = bh % H_;
    float* opart = (s == 0) ? o0 : (s == 1) ? o1 : (s == 2) ? o2 : o3;
    float* lpart = (s == 0) ? l0 : (s == 1) ? l1 : (s == 2) ? l2 : l3;
    const int tid  = threadIdx.x;
    const int lane = tid & 63;
    const int wv   = tid >> 6;
    const int half = lane >> 5;     // 0/1
    const int n32  = lane & 31;     // q-column of this lane

    __shared__ __align__(16) ushort KVs[2][64][72];
    ushort (&Ks)[64][72] = KVs[0];      // [key SLOT][dim]  (slot = swap23(key))
    ushort (&Vs)[64][72] = KVs[1];      // [dim][key]       (linear, transposed)

    const size_t hs  = (size_t)P_ * HD_;
    const int    kv0 = s * (P_ / nsp);
    const ushort* qg = qkv + ((size_t)(0 * B_ + b) * H_ + h) * hs + (size_t)(p0 + wv * 32) * HD_;
    const ushort* kg = qkv + ((size_t)(1 * B_ + b) * H_ + h) * hs + (size_t)kv0 * HD_;
    const ushort* vg = qkv + ((size_t)(2 * B_ + b) * H_ + h) * hs + (size_t)kv0 * HD_;

    // Q fragments (B-operand of swapped QK): B[k=8*half+j][n=q=n32].
    short8 aq[4];
#pragma unroll
    for (int ks2 = 0; ks2 < 4; ks2++)
        aq[ks2] = *(const short8*)(qg + (size_t)n32 * HD_ + ks2 * 16 + half * 8);

    float lsum = 0.f;
    f32x16 oaccT[2];
#pragma unroll
    for (int nt = 0; nt < 2; nt++)
#pragma unroll
        for (int r = 0; r < 16; r++) oaccT[nt][r] = 0.f;

    const int kr = tid >> 3, kc8 = tid & 7;
    const int krs = swap23(kr);          // K staging slot (swap23(kr+32)=krs+32)
    const int vd = tid & 63,  vkh = tid >> 6;

    uint4  kpre[2];
    ushort vpre[16];
    auto load_tile = [&](int kt) {
        const ushort* kg_t = kg + (size_t)kt * 64 * HD_;
        const ushort* vg_t = vg + (size_t)kt * 64 * HD_;
        kpre[0] = *(const uint4*)(kg_t + (size_t)kr * HD_ + kc8 * 8);
        kpre[1] = *(const uint4*)(kg_t + (size_t)(kr + 32) * HD_ + kc8 * 8);
#pragma unroll
        for (int j = 0; j < 16; j++)
            vpre[j] = vg_t[(size_t)(vkh * 16 + j) * HD_ + vd];
    };

    load_tile(0);
    const int NT = (P_ / 64) / nsp;
    for (int kt = 0; kt < NT; kt++) {
        __syncthreads();
        *(uint4*)&Ks[krs][kc8 * 8]      = kpre[0];
        *(uint4*)&Ks[krs + 32][kc8 * 8] = kpre[1];
        *(short8*)&Vs[vd][vkh * 16]     = *(short8*)&vpre[0];
        *(short8*)&Vs[vd][vkh * 16 + 8] = *(short8*)&vpre[8];
        __syncthreads();
        if (kt + 1 < NT) load_tile(kt + 1);

        // Per 32-key block: S^T, softmax, pack P^T B-frags in registers.
        u32x4 pw[2][2];      // [nt][kp2] -> 4 dwords = short8 B-frag
#pragma unroll
        for (int nt = 0; nt < 2; nt++) {
            f32x16 sc;
#pragma unroll
            for (int r = 0; r < 16; r++) sc[r] = 0.f;
#pragma unroll
            for (int ks2 = 0; ks2 < 4; ks2++) {
                short8 kb2 = *(const short8*)&Ks[nt * 32 + n32][ks2 * 16 + half * 8];
                sc = __builtin_amdgcn_mfma_f32_32x32x16_bf16(kb2, aq[ks2], sc, 0, 0, 0);
            }
            float p[16];
#pragma unroll
            for (int r = 0; r < 16; r++) {
                p[r] = __expf(fminf(sc[r], 60.f));
                lsum += p[r];
            }
#pragma unroll
            for (int kp2 = 0; kp2 < 2; kp2++)
#pragma unroll
                for (int i = 0; i < 4; i++)
                    pw[nt][kp2][i] = pk2bf(p[kp2 * 8 + 2 * i], p[kp2 * 8 + 2 * i + 1]);
        }

        // O^T(64d x 32q) += V^T(d x key) @ P^T(key x q); A from Vs[dim][key].
#pragma unroll
        for (int kstep = 0; kstep < 4; kstep++) {
            short8 pb = __builtin_bit_cast(short8, pw[kstep >> 1][kstep & 1]);
#pragma unroll
            for (int ntd = 0; ntd < 2; ntd++) {
                short8 av = *(const short8*)&Vs[ntd * 32 + n32][kstep * 16 + half * 8];
                oaccT[ntd] = __builtin_amdgcn_mfma_f32_32x32x16_bf16(av, pb, oaccT[ntd], 0, 0, 0);
            }
        }
    }

    // Row-sum: lane-local accumulation + one cross-half exchange.
    lsum += __shfl_xor(lsum, 32, 64);
    if (lane < 32)
        lpart[(size_t)bh * P_ + p0 + wv * 32 + lane] = lsum;

    // O^T -> O transpose through freed K/V LDS (per-wave 32x36 f32 scratch).
    __syncthreads();   // all waves done reading Ks/Vs
    float* scr = (float*)&KVs[0][0][0] + wv * 1152;
#pragma unroll
    for (int ntd = 0; ntd < 2; ntd++) {
#pragma unroll
        for (int r = 0; r < 16; r++)
            scr[n32 * 36 + (r & 3) + 8 * (r >> 2) + 4 * half] = oaccT[ntd][r];
        // In-wave DS ordering: writes above complete before reads below.
#pragma unroll
        for (int i = 0; i < 4; i++) {
            int ql = i * 8 + (lane >> 3);
            int c4 = lane & 7;
            float4 v = *(const float4*)&scr[ql * 36 + c4 * 4];
            *(float4*)(opart + ((size_t)bh * P_ + p0 + wv * 32 + ql) * HD_ + ntd * 32 + c4 * 4) = v;
        }
    }
}

// ===========================================================================
// Kernel 3: LayerNorm over D=768, fused split-combine (2- or 4-way):
// v = (sum_s o_s) / (sum_s l_s). Sole owner of normalization.
// ===========================================================================
__global__ __launch_bounds__(256) void ln_o(const float* __restrict__ o0,
                                            const float* __restrict__ o1,
                                            const float* __restrict__ o2,
                                            const float* __restrict__ o3,
                                            const float* __restrict__ l0,
                                            const float* __restrict__ l1,
                                            const float* __restrict__ l2,
                                            const float* __restrict__ l3,
                                            const int ns,
                                            ushort* __restrict__ lnb,
                                            const float* __restrict__ osc,
                                            const float* __restrict__ ob) {
    __shared__ float red[4];
    __shared__ float red2[4];
    const int row = blockIdx.x;          // b*P + p
    const int b   = row >> 11;
    const int p   = row & (P_ - 1);
    const int tid = threadIdx.x;

    auto src = [&](int d) {
        int h = d >> 6;
        size_t lr  = (size_t)(b * H_ + h) * P_ + p;
        size_t idx = lr * HD_ + (d & 63);
        float num = o0[idx] + o1[idx];
        float den = l0[lr] + l1[lr];
        if (ns == 4) { num += o2[idx] + o3[idx]; den += l2[lr] + l3[lr]; }
        return num / den;
    };
    float v0 = src(tid);
    float v1 = src(tid + 256);
    float v2 = src(tid + 512);
    float s = v0 + v1 + v2;
#pragma unroll
    for (int o = 32; o > 0; o >>= 1) s += __shfl_xor(s, o, 64);
    if ((tid & 63) == 0) red[tid >> 6] = s;
    __syncthreads();
    float mean = (red[0] + red[1] + red[2] + red[3]) * (1.0f / 768.0f);
    float d0 = v0 - mean, d1 = v1 - mean, d2 = v2 - mean;
    float sq = d0 * d0 + d1 * d1 + d2 * d2;
#pragma unroll
    for (int o = 32; o > 0; o >>= 1) sq += __shfl_xor(sq, o, 64);
    if ((tid & 63) == 0) red2[tid >> 6] = sq;
    __syncthreads();
    float var = (red2[0] + red2[1] + red2[2] + red2[3]) * (1.0f / 768.0f);
    float inv = rsqrtf(var + 1e-6f);
    const size_t base = (size_t)row * D_;
    lnb[base + tid]       = f2bf(d0 * inv * osc[tid]       + ob[tid]);
    lnb[base + tid + 256] = f2bf(d1 * inv * osc[tid + 256] + ob[tid + 256]);
    lnb[base + tid + 512] = f2bf(d2 * inv * osc[tid + 512] + ob[tid + 512]);
}

// ===========================================================================
// Kernel 4: out = ln_buf(bf16) @ W_out + b_out. 64x64 tile. (unchanged)
// ===========================================================================
__global__ __launch_bounds__(256) void gemm_out_mfma(
        const ushort* __restrict__ a, const float* __restrict__ w,
        const float* __restrict__ bias, float* __restrict__ out) {
    __shared__ __align__(16) ushort As[64][40];
    __shared__ __align__(16) ushort Bs[64][40];

    const int tid  = threadIdx.x;
    const int lane = tid & 63;
    const int wv   = tid >> 6;
    const int quad = lane >> 4;
    const int col  = lane & 15;
    const int wr   = (wv >> 1) * 32;
    const int wc   = (wv & 1) * 32;
    const int rowBase = blockIdx.y * 64;
    const int colBase = blockIdx.x * 64;

    const int am  = tid >> 2, ac8 = tid & 3;
    const int nB  = tid & 63, kq = tid >> 6;

    uint4 apre;
    float bpre[8];
    auto load_tile = [&](int kt) {
        const int k0 = kt * 32;
        apre = *(const uint4*)(a + (size_t)(rowBase + am) * D_ + k0 + ac8 * 8);
#pragma unroll
        for (int j = 0; j < 8; j++)
            bpre[j] = w[(size_t)(k0 + kq * 8 + j) * D_ + colBase + nB];
    };

    f32x4 acc[2][2];
#pragma unroll
    for (int i = 0; i < 2; i++)
#pragma unroll
        for (int j = 0; j < 2; j++) acc[i][j] = (f32x4){0.f, 0.f, 0.f, 0.f};

    load_tile(0);
    const int NT = D_ / 32;
    for (int kt = 0; kt < NT; kt++) {
        __syncthreads();
        *(uint4*)&As[am][ac8 * 8] = apre;
        {
            ushort us[8];
#pragma unroll
            for (int j = 0; j < 8; j++) us[j] = f2bf(bpre[j]);
            *(short8*)&Bs[nB][kq * 8] = *(short8*)&us[0];
        }
        __syncthreads();
        if (kt + 1 < NT) load_tile(kt + 1);

        short8 af[2], bf[2];
#pragma unroll
        for (int mt = 0; mt < 2; mt++) af[mt] = *(const short8*)&As[wr + mt * 16 + col][quad * 8];
#pragma unroll
        for (int nt = 0; nt < 2; nt++) bf[nt] = *(const short8*)&Bs[wc + nt * 16 + col][quad * 8];
#pragma unroll
        for (int mt = 0; mt < 2; mt++)
#pragma unroll
            for (int nt = 0; nt < 2; nt++)
                acc[mt][nt] = __builtin_amdgcn_mfma_f32_16x16x32_bf16(af[mt], bf[nt], acc[mt][nt], 0, 0, 0);
    }

    float b2[2];
#pragma unroll
    for (int nt = 0; nt < 2; nt++) b2[nt] = bias[colBase + wc + nt * 16 + col];
#pragma unroll
    for (int mt = 0; mt < 2; mt++) {
#pragma unroll
        for (int r = 0; r < 4; r++) {
            int m = rowBase + wr + mt * 16 + quad * 4 + r;
            float* dst = out + (size_t)m * D_ + colBase + wc;
#pragma unroll
            for (int nt = 0; nt < 2; nt++)
                dst[nt * 16 + col] = acc[mt][nt][r] + b2[nt];
        }
    }
}

// ---------------------------------------------------------------------------
extern "C" void kernel_launch(void* const* d_in, const int* in_sizes, int n_in,
                              void* d_out, int out_size, void* d_ws, size_t ws_size,
                              hipStream_t stream) {
    const float* x    = (const float*)d_in[0];
    const float* Wqkv = (const float*)d_in[1];
    const float* qs   = (const float*)d_in[2];
    const float* qb   = (const float*)d_in[3];
    const float* ks   = (const float*)d_in[4];
    const float* kb   = (const float*)d_in[5];
    const float* osc  = (const float*)d_in[6];
    const float* ob   = (const float*)d_in[7];
    const float* Wout = (const float*)d_in[8];
    const float* bout = (const float*)d_in[9];
    float* out = (float*)d_out;

    // Workspace: qkv bf16 18.9MB | (nsp-1) fp32 O-partials | nsp l-partials.
    // Last partial lives in d_out (fp32, exactly B*P*D elements).
    // nsp=2 layout is byte-identical to the verified 208us session's plan;
    // nsp=4 (57.4MB) engages only if ws_size allows.
    ushort* qkv = (ushort*)d_ws;
    const size_t qkvE = (size_t)3 * B_ * H_ * P_ * HD_;   // elements
    const size_t oE   = (size_t)B_ * H_ * P_ * HD_;       // fp32 elements
    const size_t lE   = (size_t)B_ * H_ * P_;
    float* base = (float*)(qkv + qkvE);
    const size_t need4 = qkvE * sizeof(ushort) + (3 * oE + 4 * lE) * sizeof(float);
    const int nsp = (ws_size >= need4) ? 4 : 2;
    float* op[4];
    float* lbase;
    if (nsp == 4) {
        op[0] = base; op[1] = base + oE; op[2] = base + 2 * oE; op[3] = out;
        lbase = base + 3 * oE;
    } else {
        op[0] = base; op[1] = out; op[2] = base; op[3] = base;
        lbase = base + oE;
    }
    float* lp[4] = {lbase, lbase + lE, lbase + 2 * lE, lbase + 3 * lE};
    ushort* ln_buf = qkv;   // overlays dead q-region after attention

    gemm_qkv_mfma<<<dim3(N1_ / 128, M_ / 128), 512, 0, stream>>>(x, Wqkv, qs, qb, ks, kb, qkv);
    attn_split<<<dim3(P_ / 128, B_ * H_, nsp), 256, 0, stream>>>(
        qkv, op[0], op[1], op[2], op[3], lp[0], lp[1], lp[2], lp[3]);
    ln_o<<<dim3(M_), 256, 0, stream>>>(
        op[0], op[1], op[2], op[3], lp[0], lp[1], lp[2], lp[3], nsp, ln_buf, osc, ob);
    gemm_out_mfma<<<dim3(D_ / 64, M_ / 64), 256, 0, stream>>>(ln_buf, Wout, bout, out);
}

// Round 5
// 206.485 us; speedup vs baseline: 1.0391x; 1.0141x over previous
//
#include <hip/hip_runtime.h>
#include <hip/hip_bf16.h>

// Problem constants (B=2, P=2048, D=768, H=12, hd=64)
#define B_  2
#define P_  2048
#define D_  768
#define H_  12
#define HD_ 64
#define M_  (B_ * P_)   // 4096
#define N1_ (3 * D_)    // 2304

typedef __attribute__((ext_vector_type(8))) short short8;    // 8 bf16 (4 VGPRs)
typedef __attribute__((ext_vector_type(4))) float f32x4;     // 16x16 MFMA acc
typedef __attribute__((ext_vector_type(16))) float f32x16;   // 32x32 MFMA acc
typedef __attribute__((ext_vector_type(4))) unsigned u32x4;
typedef unsigned short ushort;

__device__ __forceinline__ ushort f2bf(float f) {
    unsigned u = __float_as_uint(f);
    u += 0x7fffu + ((u >> 16) & 1u);   // RNE
    return (ushort)(u >> 16);
}

// Swap bits 2 and 3 of a slot index (involution). Staging K rows at slot
// swap23(kr) makes the 32x32 MFMA C-layout's half-interleaved row order come
// out as the exact PV B-fragment element order — no cross-lane exchange.
__device__ __forceinline__ int swap23(int s) {
    return (s & ~12) | ((s & 4) << 1) | ((s & 8) >> 1);
}

// Q pre-scale: hd^-0.5 * log2(e) — attn uses exp2 directly (v_exp_f32 is 2^x).
#define QSC_ (0.125f * 1.44269504088896340736f)

// ===========================================================================
// Kernel 1: qkv = x @ W_qkv (bf16 MFMA) + fused per-head QK-LayerNorm.
// 128x128 tile, BK=32, 512 threads / 8 waves (4x2).
// ===========================================================================
__global__ __launch_bounds__(512) void gemm_qkv_mfma(
        const float* __restrict__ x, const float* __restrict__ w,
        const float* __restrict__ qs, const float* __restrict__ qb,
        const float* __restrict__ ks, const float* __restrict__ kb,
        ushort* __restrict__ qkv) {
    __shared__ __align__(16) ushort As[128][40];
    __shared__ __align__(16) ushort Bs[128][40];

    const int tid  = threadIdx.x;
    const int lane = tid & 63;
    const int wv   = tid >> 6;            // 0..7
    const int quad = lane >> 4;
    const int col  = lane & 15;
    const int wr   = (wv >> 1) * 32;
    const int wc   = (wv & 1) * 64;
    const int rowBase = blockIdx.y * 128;
    const int colBase = blockIdx.x * 128;

    const int am0 = tid >> 3, ac4 = tid & 7;
    const int nB  = tid & 127, kq = tid >> 7;

    float4 apre[2];
    float  bpre[8];
    auto load_tile = [&](int kt) {
        const int k0 = kt * 32;
        apre[0] = *(const float4*)(x + (size_t)(rowBase + am0) * D_ + k0 + ac4 * 4);
        apre[1] = *(const float4*)(x + (size_t)(rowBase + am0 + 64) * D_ + k0 + ac4 * 4);
#pragma unroll
        for (int j = 0; j < 8; j++)
            bpre[j] = w[(size_t)(k0 + kq * 8 + j) * N1_ + colBase + nB];
    };

    f32x4 acc[2][4];
#pragma unroll
    for (int i = 0; i < 2; i++)
#pragma unroll
        for (int j = 0; j < 4; j++) acc[i][j] = (f32x4){0.f, 0.f, 0.f, 0.f};

    load_tile(0);
    const int NT = D_ / 32;
    for (int kt = 0; kt < NT; kt++) {
        __syncthreads();
        {
            ushort u0[4] = {f2bf(apre[0].x), f2bf(apre[0].y), f2bf(apre[0].z), f2bf(apre[0].w)};
            ushort u1[4] = {f2bf(apre[1].x), f2bf(apre[1].y), f2bf(apre[1].z), f2bf(apre[1].w)};
            *(uint2*)&As[am0][ac4 * 4]      = *(uint2*)u0;
            *(uint2*)&As[am0 + 64][ac4 * 4] = *(uint2*)u1;
            ushort us[8];
#pragma unroll
            for (int j = 0; j < 8; j++) us[j] = f2bf(bpre[j]);
            *(short8*)&Bs[nB][kq * 8] = *(short8*)&us[0];
        }
        __syncthreads();
        if (kt + 1 < NT) load_tile(kt + 1);

        short8 af[2], bf[4];
#pragma unroll
        for (int mt = 0; mt < 2; mt++) af[mt] = *(const short8*)&As[wr + mt * 16 + col][quad * 8];
#pragma unroll
        for (int nt = 0; nt < 4; nt++) bf[nt] = *(const short8*)&Bs[wc + nt * 16 + col][quad * 8];
#pragma unroll
        for (int mt = 0; mt < 2; mt++)
#pragma unroll
            for (int nt = 0; nt < 4; nt++)
                acc[mt][nt] = __builtin_amdgcn_mfma_f32_16x16x32_bf16(af[mt], bf[nt], acc[mt][nt], 0, 0, 0);
    }

    const int comp = colBase / D_;
    const int rem  = colBase + wc - comp * D_;
    const int h    = rem >> 6;
    float sc4[4] = {0, 0, 0, 0}, bi4[4] = {0, 0, 0, 0};
    if (comp == 0) {
#pragma unroll
        for (int nt = 0; nt < 4; nt++) { sc4[nt] = qs[nt * 16 + col]; bi4[nt] = qb[nt * 16 + col]; }
    } else if (comp == 1) {
#pragma unroll
        for (int nt = 0; nt < 4; nt++) { sc4[nt] = ks[nt * 16 + col]; bi4[nt] = kb[nt * 16 + col]; }
    }

#pragma unroll
    for (int mt = 0; mt < 2; mt++) {
#pragma unroll
        for (int r = 0; r < 4; r++) {
            int m  = rowBase + wr + mt * 16 + quad * 4 + r;
            int bb = m >> 11;
            int p  = m & 2047;
            float v0 = acc[mt][0][r], v1 = acc[mt][1][r], v2 = acc[mt][2][r], v3 = acc[mt][3][r];
            if (comp < 2) {
                float s = v0 + v1 + v2 + v3;
#pragma unroll
                for (int off = 1; off < 16; off <<= 1) s += __shfl_xor(s, off, 64);
                float mean = s * (1.0f / 64.0f);
                float d0 = v0 - mean, d1 = v1 - mean, d2 = v2 - mean, d3 = v3 - mean;
                float sq = d0 * d0 + d1 * d1 + d2 * d2 + d3 * d3;
#pragma unroll
                for (int off = 1; off < 16; off <<= 1) sq += __shfl_xor(sq, off, 64);
                float inv = rsqrtf(sq * (1.0f / 64.0f) + 1e-6f);
                v0 = d0 * inv * sc4[0] + bi4[0];
                v1 = d1 * inv * sc4[1] + bi4[1];
                v2 = d2 * inv * sc4[2] + bi4[2];
                v3 = d3 * inv * sc4[3] + bi4[3];
                if (comp == 0) { v0 *= QSC_; v1 *= QSC_; v2 *= QSC_; v3 *= QSC_; }
            }
            size_t base = ((((size_t)comp * B_ + bb) * H_ + h) * P_ + p) * HD_;
            qkv[base +  0 + col] = f2bf(v0);
            qkv[base + 16 + col] = f2bf(v1);
            qkv[base + 32 + col] = f2bf(v2);
            qkv[base + 48 + col] = f2bf(v3);
        }
    }
}

// ===========================================================================
// Kernel 2: flash attention, swapped-operand QK^T; P^T PV-fragments built
// entirely in-register via the K-slot bit2<->bit3 staging permutation.
// Block = 128 q rows, 4 waves; wave owns 32 q. Split-K over gridDim.z.
//
// S^T = mfma(A=K, B=Q): C col = q = lane&31, row = key SLOT =
//   (reg&3)+8*(reg>>2)+4*half. K row kr is staged at slot swap23(kr), so
//   slot s holds global key swap23(s). Element j of PV's B-frag (needs key
//   kp2*16+8h+j) = p[kp2*8+j].  (no cross-lane ops)
// Softmax: Q pre-scaled by log2e -> p = exp2(sc) via one v_exp_f32; packing
//   via v_cvt_pk_bf16_f32 (1 op/word, RNE — same rounding as f2bf).
// O^T = mfma(A=V^T from Vs[dim][key] linear, B=P^T). No P LDS buffer.
// ===========================================================================
__global__ __launch_bounds__(256) void attn_split(const ushort* __restrict__ qkv,
                                                  float* __restrict__ o0, float* __restrict__ o1,
                                                  float* __restrict__ o2, float* __restrict__ o3,
                                                  float* __restrict__ l0, float* __restrict__ l1,
                                                  float* __restrict__ l2, float* __restrict__ l3) {
    const int p0  = blockIdx.x * 128;
    const int bh  = blockIdx.y;
    const int s   = blockIdx.z;
    const int nsp = gridDim.z;           // 2 or 4
    const int b   = bh / H_, h = bh % H_;
    float* opart = (s == 0) ? o0 : (s == 1) ? o1 : (s == 2) ? o2 : o3;
    float* lpart = (s == 0) ? l0 : (s == 1) ? l1 : (s == 2) ? l2 : l3;
    const int tid  = threadIdx.x;
    const int lane = tid & 63;
    const int wv   = tid >> 6;
    const int half = lane >> 5;     // 0/1
    const int n32  = lane & 31;     // q-column of this lane

    __shared__ __align__(16) ushort KVs[2][64][72];
    ushort (&Ks)[64][72] = KVs[0];      // [key SLOT][dim]  (slot = swap23(key))
    ushort (&Vs)[64][72] = KVs[1];      // [dim][key]       (linear, transposed)

    const size_t hs  = (size_t)P_ * HD_;
    const int    kv0 = s * (P_ / nsp);
    const ushort* qg = qkv + ((size_t)(0 * B_ + b) * H_ + h) * hs + (size_t)(p0 + wv * 32) * HD_;
    const ushort* kg = qkv + ((size_t)(1 * B_ + b) * H_ + h) * hs + (size_t)kv0 * HD_;
    const ushort* vg = qkv + ((size_t)(2 * B_ + b) * H_ + h) * hs + (size_t)kv0 * HD_;

    // Q fragments (B-operand of swapped QK): B[k=8*half+j][n=q=n32].
    short8 aq[4];
#pragma unroll
    for (int ks2 = 0; ks2 < 4; ks2++)
        aq[ks2] = *(const short8*)(qg + (size_t)n32 * HD_ + ks2 * 16 + half * 8);

    float lsum = 0.f;
    f32x16 oaccT[2];
#pragma unroll
    for (int nt = 0; nt < 2; nt++)
#pragma unroll
        for (int r = 0; r < 16; r++) oaccT[nt][r] = 0.f;

    const int kr = tid >> 3, kc8 = tid & 7;
    const int krs = swap23(kr);          // K staging slot (swap23(kr+32)=krs+32)
    const int vd = tid & 63,  vkh = tid >> 6;

    uint4  kpre[2];
    ushort vpre[16];
    auto load_tile = [&](int kt) {
        const ushort* kg_t = kg + (size_t)kt * 64 * HD_;
        const ushort* vg_t = vg + (size_t)kt * 64 * HD_;
        kpre[0] = *(const uint4*)(kg_t + (size_t)kr * HD_ + kc8 * 8);
        kpre[1] = *(const uint4*)(kg_t + (size_t)(kr + 32) * HD_ + kc8 * 8);
#pragma unroll
        for (int j = 0; j < 16; j++)
            vpre[j] = vg_t[(size_t)(vkh * 16 + j) * HD_ + vd];
    };

    load_tile(0);
    const int NT = (P_ / 64) / nsp;
    for (int kt = 0; kt < NT; kt++) {
        __syncthreads();
        *(uint4*)&Ks[krs][kc8 * 8]      = kpre[0];
        *(uint4*)&Ks[krs + 32][kc8 * 8] = kpre[1];
        *(short8*)&Vs[vd][vkh * 16]     = *(short8*)&vpre[0];
        *(short8*)&Vs[vd][vkh * 16 + 8] = *(short8*)&vpre[8];
        __syncthreads();
        if (kt + 1 < NT) load_tile(kt + 1);

        // Per 32-key block: S^T, softmax (exp2), pack P^T B-frags in registers.
        u32x4 pw[2][2];      // [nt][kp2] -> 4 dwords = short8 B-frag
#pragma unroll
        for (int nt = 0; nt < 2; nt++) {
            f32x16 sc;
#pragma unroll
            for (int r = 0; r < 16; r++) sc[r] = 0.f;
#pragma unroll
            for (int ks2 = 0; ks2 < 4; ks2++) {
                short8 kb2 = *(const short8*)&Ks[nt * 32 + n32][ks2 * 16 + half * 8];
                sc = __builtin_amdgcn_mfma_f32_32x32x16_bf16(kb2, aq[ks2], sc, 0, 0, 0);
            }
            float p[16];
#pragma unroll
            for (int r = 0; r < 16; r++) {
                p[r] = __builtin_amdgcn_exp2f(fminf(sc[r], 86.5f));
                lsum += p[r];
            }
            unsigned cw[8];
#pragma unroll
            for (int i = 0; i < 8; i++)
                asm("v_cvt_pk_bf16_f32 %0, %1, %2"
                    : "=v"(cw[i]) : "v"(p[2 * i]), "v"(p[2 * i + 1]));
            pw[nt][0][0] = cw[0]; pw[nt][0][1] = cw[1]; pw[nt][0][2] = cw[2]; pw[nt][0][3] = cw[3];
            pw[nt][1][0] = cw[4]; pw[nt][1][1] = cw[5]; pw[nt][1][2] = cw[6]; pw[nt][1][3] = cw[7];
        }

        // O^T(64d x 32q) += V^T(d x key) @ P^T(key x q); A from Vs[dim][key].
#pragma unroll
        for (int kstep = 0; kstep < 4; kstep++) {
            short8 pb = __builtin_bit_cast(short8, pw[kstep >> 1][kstep & 1]);
#pragma unroll
            for (int ntd = 0; ntd < 2; ntd++) {
                short8 av = *(const short8*)&Vs[ntd * 32 + n32][kstep * 16 + half * 8];
                oaccT[ntd] = __builtin_amdgcn_mfma_f32_32x32x16_bf16(av, pb, oaccT[ntd], 0, 0, 0);
            }
        }
    }

    // Row-sum: lane-local accumulation + one cross-half exchange.
    lsum += __shfl_xor(lsum, 32, 64);
    if (lane < 32)
        lpart[(size_t)bh * P_ + p0 + wv * 32 + lane] = lsum;

    // O^T -> O transpose through freed K/V LDS (per-wave 32x36 f32 scratch).
    __syncthreads();   // all waves done reading Ks/Vs
    float* scr = (float*)&KVs[0][0][0] + wv * 1152;
#pragma unroll
    for (int ntd = 0; ntd < 2; ntd++) {
#pragma unroll
        for (int r = 0; r < 16; r++)
            scr[n32 * 36 + (r & 3) + 8 * (r >> 2) + 4 * half] = oaccT[ntd][r];
        // In-wave DS ordering: writes above complete before reads below.
#pragma unroll
        for (int i = 0; i < 4; i++) {
            int ql = i * 8 + (lane >> 3);
            int c4 = lane & 7;
            float4 v = *(const float4*)&scr[ql * 36 + c4 * 4];
            *(float4*)(opart + ((size_t)bh * P_ + p0 + wv * 32 + ql) * HD_ + ntd * 32 + c4 * 4) = v;
        }
    }
}

// ===========================================================================
// Kernel 3: LayerNorm over D=768, fused split-combine (2- or 4-way):
// v = (sum_s o_s) / (sum_s l_s). Sole owner of normalization.
// ===========================================================================
__global__ __launch_bounds__(256) void ln_o(const float* __restrict__ o0,
                                            const float* __restrict__ o1,
                                            const float* __restrict__ o2,
                                            const float* __restrict__ o3,
                                            const float* __restrict__ l0,
                                            const float* __restrict__ l1,
                                            const float* __restrict__ l2,
                                            const float* __restrict__ l3,
                                            const int ns,
                                            ushort* __restrict__ lnb,
                                            const float* __restrict__ osc,
                                            const float* __restrict__ ob) {
    __shared__ float red[4];
    __shared__ float red2[4];
    const int row = blockIdx.x;          // b*P + p
    const int b   = row >> 11;
    const int p   = row & (P_ - 1);
    const int tid = threadIdx.x;

    auto src = [&](int d) {
        int h = d >> 6;
        size_t lr  = (size_t)(b * H_ + h) * P_ + p;
        size_t idx = lr * HD_ + (d & 63);
        float num = o0[idx] + o1[idx];
        float den = l0[lr] + l1[lr];
        if (ns == 4) { num += o2[idx] + o3[idx]; den += l2[lr] + l3[lr]; }
        return num / den;
    };
    float v0 = src(tid);
    float v1 = src(tid + 256);
    float v2 = src(tid + 512);
    float s = v0 + v1 + v2;
#pragma unroll
    for (int o = 32; o > 0; o >>= 1) s += __shfl_xor(s, o, 64);
    if ((tid & 63) == 0) red[tid >> 6] = s;
    __syncthreads();
    float mean = (red[0] + red[1] + red[2] + red[3]) * (1.0f / 768.0f);
    float d0 = v0 - mean, d1 = v1 - mean, d2 = v2 - mean;
    float sq = d0 * d0 + d1 * d1 + d2 * d2;
#pragma unroll
    for (int o = 32; o > 0; o >>= 1) sq += __shfl_xor(sq, o, 64);
    if ((tid & 63) == 0) red2[tid >> 6] = sq;
    __syncthreads();
    float var = (red2[0] + red2[1] + red2[2] + red2[3]) * (1.0f / 768.0f);
    float inv = rsqrtf(var + 1e-6f);
    const size_t base = (size_t)row * D_;
    lnb[base + tid]       = f2bf(d0 * inv * osc[tid]       + ob[tid]);
    lnb[base + tid + 256] = f2bf(d1 * inv * osc[tid + 256] + ob[tid + 256]);
    lnb[base + tid + 512] = f2bf(d2 * inv * osc[tid + 512] + ob[tid + 512]);
}

// ===========================================================================
// Kernel 4: out = ln_buf(bf16) @ W_out + b_out. 64x64 tile. (unchanged)
// ===========================================================================
__global__ __launch_bounds__(256) void gemm_out_mfma(
        const ushort* __restrict__ a, const float* __restrict__ w,
        const float* __restrict__ bias, float* __restrict__ out) {
    __shared__ __align__(16) ushort As[64][40];
    __shared__ __align__(16) ushort Bs[64][40];

    const int tid  = threadIdx.x;
    const int lane = tid & 63;
    const int wv   = tid >> 6;
    const int quad = lane >> 4;
    const int col  = lane & 15;
    const int wr   = (wv >> 1) * 32;
    const int wc   = (wv & 1) * 32;
    const int rowBase = blockIdx.y * 64;
    const int colBase = blockIdx.x * 64;

    const int am  = tid >> 2, ac8 = tid & 3;
    const int nB  = tid & 63, kq = tid >> 6;

    uint4 apre;
    float bpre[8];
    auto load_tile = [&](int kt) {
        const int k0 = kt * 32;
        apre = *(const uint4*)(a + (size_t)(rowBase + am) * D_ + k0 + ac8 * 8);
#pragma unroll
        for (int j = 0; j < 8; j++)
            bpre[j] = w[(size_t)(k0 + kq * 8 + j) * D_ + colBase + nB];
    };

    f32x4 acc[2][2];
#pragma unroll
    for (int i = 0; i < 2; i++)
#pragma unroll
        for (int j = 0; j < 2; j++) acc[i][j] = (f32x4){0.f, 0.f, 0.f, 0.f};

    load_tile(0);
    const int NT = D_ / 32;
    for (int kt = 0; kt < NT; kt++) {
        __syncthreads();
        *(uint4*)&As[am][ac8 * 8] = apre;
        {
            ushort us[8];
#pragma unroll
            for (int j = 0; j < 8; j++) us[j] = f2bf(bpre[j]);
            *(short8*)&Bs[nB][kq * 8] = *(short8*)&us[0];
        }
        __syncthreads();
        if (kt + 1 < NT) load_tile(kt + 1);

        short8 af[2], bf[2];
#pragma unroll
        for (int mt = 0; mt < 2; mt++) af[mt] = *(const short8*)&As[wr + mt * 16 + col][quad * 8];
#pragma unroll
        for (int nt = 0; nt < 2; nt++) bf[nt] = *(const short8*)&Bs[wc + nt * 16 + col][quad * 8];
#pragma unroll
        for (int mt = 0; mt < 2; mt++)
#pragma unroll
            for (int nt = 0; nt < 2; nt++)
                acc[mt][nt] = __builtin_amdgcn_mfma_f32_16x16x32_bf16(af[mt], bf[nt], acc[mt][nt], 0, 0, 0);
    }

    float b2[2];
#pragma unroll
    for (int nt = 0; nt < 2; nt++) b2[nt] = bias[colBase + wc + nt * 16 + col];
#pragma unroll
    for (int mt = 0; mt < 2; mt++) {
#pragma unroll
        for (int r = 0; r < 4; r++) {
            int m = rowBase + wr + mt * 16 + quad * 4 + r;
            float* dst = out + (size_t)m * D_ + colBase + wc;
#pragma unroll
            for (int nt = 0; nt < 2; nt++)
                dst[nt * 16 + col] = acc[mt][nt][r] + b2[nt];
        }
    }
}

// ---------------------------------------------------------------------------
extern "C" void kernel_launch(void* const* d_in, const int* in_sizes, int n_in,
                              void* d_out, int out_size, void* d_ws, size_t ws_size,
                              hipStream_t stream) {
    const float* x    = (const float*)d_in[0];
    const float* Wqkv = (const float*)d_in[1];
    const float* qs   = (const float*)d_in[2];
    const float* qb   = (const float*)d_in[3];
    const float* ks   = (const float*)d_in[4];
    const float* kb   = (const float*)d_in[5];
    const float* osc  = (const float*)d_in[6];
    const float* ob   = (const float*)d_in[7];
    const float* Wout = (const float*)d_in[8];
    const float* bout = (const float*)d_in[9];
    float* out = (float*)d_out;

    // Workspace: qkv bf16 18.9MB | (nsp-1) fp32 O-partials | nsp l-partials.
    // Last partial lives in d_out (fp32, exactly B*P*D elements).
    ushort* qkv = (ushort*)d_ws;
    const size_t qkvE = (size_t)3 * B_ * H_ * P_ * HD_;   // elements
    const size_t oE   = (size_t)B_ * H_ * P_ * HD_;       // fp32 elements
    const size_t lE   = (size_t)B_ * H_ * P_;
    float* base = (float*)(qkv + qkvE);
    const size_t need4 = qkvE * sizeof(ushort) + (3 * oE + 4 * lE) * sizeof(float);
    const int nsp = (ws_size >= need4) ? 4 : 2;
    float* op[4];
    float* lbase;
    if (nsp == 4) {
        op[0] = base; op[1] = base + oE; op[2] = base + 2 * oE; op[3] = out;
        lbase = base + 3 * oE;
    } else {
        op[0] = base; op[1] = out; op[2] = base; op[3] = base;
        lbase = base + oE;
    }
    float* lp[4] = {lbase, lbase + lE, lbase + 2 * lE, lbase + 3 * lE};
    ushort* ln_buf = qkv;   // overlays dead q-region after attention

    gemm_qkv_mfma<<<dim3(N1_ / 128, M_ / 128), 512, 0, stream>>>(x, Wqkv, qs, qb, ks, kb, qkv);
    attn_split<<<dim3(P_ / 128, B_ * H_, nsp), 256, 0, stream>>>(
        qkv, op[0], op[1], op[2], op[3], lp[0], lp[1], lp[2], lp[3]);
    ln_o<<<dim3(M_), 256, 0, stream>>>(
        op[0], op[1], op[2], op[3], lp[0], lp[1], lp[2], lp[3], nsp, ln_buf, osc, ob);
    gemm_out_mfma<<<dim3(D_ / 64, M_ / 64), 256, 0, stream>>>(ln_buf, Wout, bout, out);
}

// Round 6
// 201.489 us; speedup vs baseline: 1.0648x; 1.0248x over previous
//
#include <hip/hip_runtime.h>
#include <hip/hip_bf16.h>

// Problem constants (B=2, P=2048, D=768, H=12, hd=64)
#define B_  2
#define P_  2048
#define D_  768
#define H_  12
#define HD_ 64
#define M_  (B_ * P_)   // 4096
#define N1_ (3 * D_)    // 2304

typedef __attribute__((ext_vector_type(8))) short short8;    // 8 bf16 (4 VGPRs)
typedef __attribute__((ext_vector_type(4))) float f32x4;     // 16x16 MFMA acc
typedef __attribute__((ext_vector_type(16))) float f32x16;   // 32x32 MFMA acc
typedef __attribute__((ext_vector_type(4))) unsigned u32x4;
typedef unsigned short ushort;

__device__ __forceinline__ ushort f2bf(float f) {
    unsigned u = __float_as_uint(f);
    u += 0x7fffu + ((u >> 16) & 1u);   // RNE
    return (ushort)(u >> 16);
}

// Pack 2 floats -> 1 dword of 2x bf16 (lo=a, hi=b), RNE. Semantics verified
// on HW by round-5 attn (passed with identical absmax).
__device__ __forceinline__ unsigned cvtpk(float a, float b) {
    unsigned r;
    asm("v_cvt_pk_bf16_f32 %0, %1, %2" : "=v"(r) : "v"(a), "v"(b));
    return r;
}

// Swap bits 2 and 3 of a slot index (involution). Staging K rows at slot
// swap23(kr) makes the 32x32 MFMA C-layout's half-interleaved row order come
// out as the exact PV B-fragment element order — no cross-lane exchange.
__device__ __forceinline__ int swap23(int s) {
    return (s & ~12) | ((s & 4) << 1) | ((s & 8) >> 1);
}

// Q pre-scale: hd^-0.5 * log2(e) — attn uses exp2 directly (v_exp_f32 is 2^x).
#define QSC_ (0.125f * 1.44269504088896340736f)

// ===========================================================================
// Kernel 1: qkv = x @ W_qkv (bf16 MFMA) + fused per-head QK-LayerNorm.
// 128x128 tile, BK=32, 512 threads / 8 waves (4x2).
// Staging conversion via v_cvt_pk_bf16_f32 (8 ops/thread/K-step, was ~80).
// ===========================================================================
__global__ __launch_bounds__(512) void gemm_qkv_mfma(
        const float* __restrict__ x, const float* __restrict__ w,
        const float* __restrict__ qs, const float* __restrict__ qb,
        const float* __restrict__ ks, const float* __restrict__ kb,
        ushort* __restrict__ qkv) {
    __shared__ __align__(16) ushort As[128][40];
    __shared__ __align__(16) ushort Bs[128][40];

    const int tid  = threadIdx.x;
    const int lane = tid & 63;
    const int wv   = tid >> 6;            // 0..7
    const int quad = lane >> 4;
    const int col  = lane & 15;
    const int wr   = (wv >> 1) * 32;
    const int wc   = (wv & 1) * 64;
    const int rowBase = blockIdx.y * 128;
    const int colBase = blockIdx.x * 128;

    const int am0 = tid >> 3, ac4 = tid & 7;
    const int nB  = tid & 127, kq = tid >> 7;

    float4 apre[2];
    float  bpre[8];
    auto load_tile = [&](int kt) {
        const int k0 = kt * 32;
        apre[0] = *(const float4*)(x + (size_t)(rowBase + am0) * D_ + k0 + ac4 * 4);
        apre[1] = *(const float4*)(x + (size_t)(rowBase + am0 + 64) * D_ + k0 + ac4 * 4);
#pragma unroll
        for (int j = 0; j < 8; j++)
            bpre[j] = w[(size_t)(k0 + kq * 8 + j) * N1_ + colBase + nB];
    };

    f32x4 acc[2][4];
#pragma unroll
    for (int i = 0; i < 2; i++)
#pragma unroll
        for (int j = 0; j < 4; j++) acc[i][j] = (f32x4){0.f, 0.f, 0.f, 0.f};

    load_tile(0);
    const int NT = D_ / 32;
    for (int kt = 0; kt < NT; kt++) {
        __syncthreads();
        {
            uint2 a0 = {cvtpk(apre[0].x, apre[0].y), cvtpk(apre[0].z, apre[0].w)};
            uint2 a1 = {cvtpk(apre[1].x, apre[1].y), cvtpk(apre[1].z, apre[1].w)};
            *(uint2*)&As[am0][ac4 * 4]      = a0;
            *(uint2*)&As[am0 + 64][ac4 * 4] = a1;
            u32x4 bb;
#pragma unroll
            for (int j = 0; j < 4; j++) bb[j] = cvtpk(bpre[2 * j], bpre[2 * j + 1]);
            *(u32x4*)&Bs[nB][kq * 8] = bb;
        }
        __syncthreads();
        if (kt + 1 < NT) load_tile(kt + 1);

        short8 af[2], bf[4];
#pragma unroll
        for (int mt = 0; mt < 2; mt++) af[mt] = *(const short8*)&As[wr + mt * 16 + col][quad * 8];
#pragma unroll
        for (int nt = 0; nt < 4; nt++) bf[nt] = *(const short8*)&Bs[wc + nt * 16 + col][quad * 8];
#pragma unroll
        for (int mt = 0; mt < 2; mt++)
#pragma unroll
            for (int nt = 0; nt < 4; nt++)
                acc[mt][nt] = __builtin_amdgcn_mfma_f32_16x16x32_bf16(af[mt], bf[nt], acc[mt][nt], 0, 0, 0);
    }

    const int comp = colBase / D_;
    const int rem  = colBase + wc - comp * D_;
    const int h    = rem >> 6;
    float sc4[4] = {0, 0, 0, 0}, bi4[4] = {0, 0, 0, 0};
    if (comp == 0) {
#pragma unroll
        for (int nt = 0; nt < 4; nt++) { sc4[nt] = qs[nt * 16 + col]; bi4[nt] = qb[nt * 16 + col]; }
    } else if (comp == 1) {
#pragma unroll
        for (int nt = 0; nt < 4; nt++) { sc4[nt] = ks[nt * 16 + col]; bi4[nt] = kb[nt * 16 + col]; }
    }

#pragma unroll
    for (int mt = 0; mt < 2; mt++) {
#pragma unroll
        for (int r = 0; r < 4; r++) {
            int m  = rowBase + wr + mt * 16 + quad * 4 + r;
            int bb = m >> 11;
            int p  = m & 2047;
            float v0 = acc[mt][0][r], v1 = acc[mt][1][r], v2 = acc[mt][2][r], v3 = acc[mt][3][r];
            if (comp < 2) {
                float s = v0 + v1 + v2 + v3;
#pragma unroll
                for (int off = 1; off < 16; off <<= 1) s += __shfl_xor(s, off, 64);
                float mean = s * (1.0f / 64.0f);
                float d0 = v0 - mean, d1 = v1 - mean, d2 = v2 - mean, d3 = v3 - mean;
                float sq = d0 * d0 + d1 * d1 + d2 * d2 + d3 * d3;
#pragma unroll
                for (int off = 1; off < 16; off <<= 1) sq += __shfl_xor(sq, off, 64);
                float inv = rsqrtf(sq * (1.0f / 64.0f) + 1e-6f);
                v0 = d0 * inv * sc4[0] + bi4[0];
                v1 = d1 * inv * sc4[1] + bi4[1];
                v2 = d2 * inv * sc4[2] + bi4[2];
                v3 = d3 * inv * sc4[3] + bi4[3];
                if (comp == 0) { v0 *= QSC_; v1 *= QSC_; v2 *= QSC_; v3 *= QSC_; }
            }
            size_t base = ((((size_t)comp * B_ + bb) * H_ + h) * P_ + p) * HD_;
            qkv[base +  0 + col] = f2bf(v0);
            qkv[base + 16 + col] = f2bf(v1);
            qkv[base + 32 + col] = f2bf(v2);
            qkv[base + 48 + col] = f2bf(v3);
        }
    }
}

// ===========================================================================
// Kernel 2: flash attention, swapped-operand QK^T; P^T PV-fragments built
// entirely in-register via the K-slot bit2<->bit3 staging permutation.
// Block = 128 q rows, 4 waves; wave owns 32 q. Split-K over gridDim.z.
// (unchanged from round 5)
// ===========================================================================
__global__ __launch_bounds__(256) void attn_split(const ushort* __restrict__ qkv,
                                                  float* __restrict__ o0, float* __restrict__ o1,
                                                  float* __restrict__ o2, float* __restrict__ o3,
                                                  float* __restrict__ l0, float* __restrict__ l1,
                                                  float* __restrict__ l2, float* __restrict__ l3) {
    const int p0  = blockIdx.x * 128;
    const int bh  = blockIdx.y;
    const int s   = blockIdx.z;
    const int nsp = gridDim.z;           // 2 or 4
    const int b   = bh / H_, h = bh % H_;
    float* opart = (s == 0) ? o0 : (s == 1) ? o1 : (s == 2) ? o2 : o3;
    float* lpart = (s == 0) ? l0 : (s == 1) ? l1 : (s == 2) ? l2 : l3;
    const int tid  = threadIdx.x;
    const int lane = tid & 63;
    const int wv   = tid >> 6;
    const int half = lane >> 5;     // 0/1
    const int n32  = lane & 31;     // q-column of this lane

    __shared__ __align__(16) ushort KVs[2][64][72];
    ushort (&Ks)[64][72] = KVs[0];      // [key SLOT][dim]  (slot = swap23(key))
    ushort (&Vs)[64][72] = KVs[1];      // [dim][key]       (linear, transposed)

    const size_t hs  = (size_t)P_ * HD_;
    const int    kv0 = s * (P_ / nsp);
    const ushort* qg = qkv + ((size_t)(0 * B_ + b) * H_ + h) * hs + (size_t)(p0 + wv * 32) * HD_;
    const ushort* kg = qkv + ((size_t)(1 * B_ + b) * H_ + h) * hs + (size_t)kv0 * HD_;
    const ushort* vg = qkv + ((size_t)(2 * B_ + b) * H_ + h) * hs + (size_t)kv0 * HD_;

    // Q fragments (B-operand of swapped QK): B[k=8*half+j][n=q=n32].
    short8 aq[4];
#pragma unroll
    for (int ks2 = 0; ks2 < 4; ks2++)
        aq[ks2] = *(const short8*)(qg + (size_t)n32 * HD_ + ks2 * 16 + half * 8);

    float lsum = 0.f;
    f32x16 oaccT[2];
#pragma unroll
    for (int nt = 0; nt < 2; nt++)
#pragma unroll
        for (int r = 0; r < 16; r++) oaccT[nt][r] = 0.f;

    const int kr = tid >> 3, kc8 = tid & 7;
    const int krs = swap23(kr);          // K staging slot (swap23(kr+32)=krs+32)
    const int vd = tid & 63,  vkh = tid >> 6;

    uint4  kpre[2];
    ushort vpre[16];
    auto load_tile = [&](int kt) {
        const ushort* kg_t = kg + (size_t)kt * 64 * HD_;
        const ushort* vg_t = vg + (size_t)kt * 64 * HD_;
        kpre[0] = *(const uint4*)(kg_t + (size_t)kr * HD_ + kc8 * 8);
        kpre[1] = *(const uint4*)(kg_t + (size_t)(kr + 32) * HD_ + kc8 * 8);
#pragma unroll
        for (int j = 0; j < 16; j++)
            vpre[j] = vg_t[(size_t)(vkh * 16 + j) * HD_ + vd];
    };

    load_tile(0);
    const int NT = (P_ / 64) / nsp;
    for (int kt = 0; kt < NT; kt++) {
        __syncthreads();
        *(uint4*)&Ks[krs][kc8 * 8]      = kpre[0];
        *(uint4*)&Ks[krs + 32][kc8 * 8] = kpre[1];
        *(short8*)&Vs[vd][vkh * 16]     = *(short8*)&vpre[0];
        *(short8*)&Vs[vd][vkh * 16 + 8] = *(short8*)&vpre[8];
        __syncthreads();
        if (kt + 1 < NT) load_tile(kt + 1);

        // Per 32-key block: S^T, softmax (exp2), pack P^T B-frags in registers.
        u32x4 pw[2][2];      // [nt][kp2] -> 4 dwords = short8 B-frag
#pragma unroll
        for (int nt = 0; nt < 2; nt++) {
            f32x16 sc;
#pragma unroll
            for (int r = 0; r < 16; r++) sc[r] = 0.f;
#pragma unroll
            for (int ks2 = 0; ks2 < 4; ks2++) {
                short8 kb2 = *(const short8*)&Ks[nt * 32 + n32][ks2 * 16 + half * 8];
                sc = __builtin_amdgcn_mfma_f32_32x32x16_bf16(kb2, aq[ks2], sc, 0, 0, 0);
            }
            float p[16];
#pragma unroll
            for (int r = 0; r < 16; r++) {
                p[r] = __builtin_amdgcn_exp2f(fminf(sc[r], 86.5f));
                lsum += p[r];
            }
#pragma unroll
            for (int kp2 = 0; kp2 < 2; kp2++)
#pragma unroll
                for (int i = 0; i < 4; i++)
                    pw[nt][kp2][i] = cvtpk(p[kp2 * 8 + 2 * i], p[kp2 * 8 + 2 * i + 1]);
        }

        // O^T(64d x 32q) += V^T(d x key) @ P^T(key x q); A from Vs[dim][key].
#pragma unroll
        for (int kstep = 0; kstep < 4; kstep++) {
            short8 pb = __builtin_bit_cast(short8, pw[kstep >> 1][kstep & 1]);
#pragma unroll
            for (int ntd = 0; ntd < 2; ntd++) {
                short8 av = *(const short8*)&Vs[ntd * 32 + n32][kstep * 16 + half * 8];
                oaccT[ntd] = __builtin_amdgcn_mfma_f32_32x32x16_bf16(av, pb, oaccT[ntd], 0, 0, 0);
            }
        }
    }

    // Row-sum: lane-local accumulation + one cross-half exchange.
    lsum += __shfl_xor(lsum, 32, 64);
    if (lane < 32)
        lpart[(size_t)bh * P_ + p0 + wv * 32 + lane] = lsum;

    // O^T -> O transpose through freed K/V LDS (per-wave 32x36 f32 scratch).
    __syncthreads();   // all waves done reading Ks/Vs
    float* scr = (float*)&KVs[0][0][0] + wv * 1152;
#pragma unroll
    for (int ntd = 0; ntd < 2; ntd++) {
#pragma unroll
        for (int r = 0; r < 16; r++)
            scr[n32 * 36 + (r & 3) + 8 * (r >> 2) + 4 * half] = oaccT[ntd][r];
        // In-wave DS ordering: writes above complete before reads below.
#pragma unroll
        for (int i = 0; i < 4; i++) {
            int ql = i * 8 + (lane >> 3);
            int c4 = lane & 7;
            float4 v = *(const float4*)&scr[ql * 36 + c4 * 4];
            *(float4*)(opart + ((size_t)bh * P_ + p0 + wv * 32 + ql) * HD_ + ntd * 32 + c4 * 4) = v;
        }
    }
}

// ===========================================================================
// Kernel 3: LayerNorm over D=768, fused split-combine (2- or 4-way):
// v = (sum_s o_s) / (sum_s l_s). Sole owner of normalization.
// ===========================================================================
__global__ __launch_bounds__(256) void ln_o(const float* __restrict__ o0,
                                            const float* __restrict__ o1,
                                            const float* __restrict__ o2,
                                            const float* __restrict__ o3,
                                            const float* __restrict__ l0,
                                            const float* __restrict__ l1,
                                            const float* __restrict__ l2,
                                            const float* __restrict__ l3,
                                            const int ns,
                                            ushort* __restrict__ lnb,
                                            const float* __restrict__ osc,
                                            const float* __restrict__ ob) {
    __shared__ float red[4];
    __shared__ float red2[4];
    const int row = blockIdx.x;          // b*P + p
    const int b   = row >> 11;
    const int p   = row & (P_ - 1);
    const int tid = threadIdx.x;

    auto src = [&](int d) {
        int h = d >> 6;
        size_t lr  = (size_t)(b * H_ + h) * P_ + p;
        size_t idx = lr * HD_ + (d & 63);
        float num = o0[idx] + o1[idx];
        float den = l0[lr] + l1[lr];
        if (ns == 4) { num += o2[idx] + o3[idx]; den += l2[lr] + l3[lr]; }
        return num / den;
    };
    float v0 = src(tid);
    float v1 = src(tid + 256);
    float v2 = src(tid + 512);
    float s = v0 + v1 + v2;
#pragma unroll
    for (int o = 32; o > 0; o >>= 1) s += __shfl_xor(s, o, 64);
    if ((tid & 63) == 0) red[tid >> 6] = s;
    __syncthreads();
    float mean = (red[0] + red[1] + red[2] + red[3]) * (1.0f / 768.0f);
    float d0 = v0 - mean, d1 = v1 - mean, d2 = v2 - mean;
    float sq = d0 * d0 + d1 * d1 + d2 * d2;
#pragma unroll
    for (int o = 32; o > 0; o >>= 1) sq += __shfl_xor(sq, o, 64);
    if ((tid & 63) == 0) red2[tid >> 6] = sq;
    __syncthreads();
    float var = (red2[0] + red2[1] + red2[2] + red2[3]) * (1.0f / 768.0f);
    float inv = rsqrtf(var + 1e-6f);
    const size_t base = (size_t)row * D_;
    lnb[base + tid]       = f2bf(d0 * inv * osc[tid]       + ob[tid]);
    lnb[base + tid + 256] = f2bf(d1 * inv * osc[tid + 256] + ob[tid + 256]);
    lnb[base + tid + 512] = f2bf(d2 * inv * osc[tid + 512] + ob[tid + 512]);
}

// ===========================================================================
// Kernel 4: out = ln_buf(bf16) @ W_out + b_out. 64x64 tile.
// Staging conversion via v_cvt_pk_bf16_f32.
// ===========================================================================
__global__ __launch_bounds__(256) void gemm_out_mfma(
        const ushort* __restrict__ a, const float* __restrict__ w,
        const float* __restrict__ bias, float* __restrict__ out) {
    __shared__ __align__(16) ushort As[64][40];
    __shared__ __align__(16) ushort Bs[64][40];

    const int tid  = threadIdx.x;
    const int lane = tid & 63;
    const int wv   = tid >> 6;
    const int quad = lane >> 4;
    const int col  = lane & 15;
    const int wr   = (wv >> 1) * 32;
    const int wc   = (wv & 1) * 32;
    const int rowBase = blockIdx.y * 64;
    const int colBase = blockIdx.x * 64;

    const int am  = tid >> 2, ac8 = tid & 3;
    const int nB  = tid & 63, kq = tid >> 6;

    uint4 apre;
    float bpre[8];
    auto load_tile = [&](int kt) {
        const int k0 = kt * 32;
        apre = *(const uint4*)(a + (size_t)(rowBase + am) * D_ + k0 + ac8 * 8);
#pragma unroll
        for (int j = 0; j < 8; j++)
            bpre[j] = w[(size_t)(k0 + kq * 8 + j) * D_ + colBase + nB];
    };

    f32x4 acc[2][2];
#pragma unroll
    for (int i = 0; i < 2; i++)
#pragma unroll
        for (int j = 0; j < 2; j++) acc[i][j] = (f32x4){0.f, 0.f, 0.f, 0.f};

    load_tile(0);
    const int NT = D_ / 32;
    for (int kt = 0; kt < NT; kt++) {
        __syncthreads();
        *(uint4*)&As[am][ac8 * 8] = apre;
        {
            u32x4 bb;
#pragma unroll
            for (int j = 0; j < 4; j++) bb[j] = cvtpk(bpre[2 * j], bpre[2 * j + 1]);
            *(u32x4*)&Bs[nB][kq * 8] = bb;
        }
        __syncthreads();
        if (kt + 1 < NT) load_tile(kt + 1);

        short8 af[2], bf[2];
#pragma unroll
        for (int mt = 0; mt < 2; mt++) af[mt] = *(const short8*)&As[wr + mt * 16 + col][quad * 8];
#pragma unroll
        for (int nt = 0; nt < 2; nt++) bf[nt] = *(const short8*)&Bs[wc + nt * 16 + col][quad * 8];
#pragma unroll
        for (int mt = 0; mt < 2; mt++)
#pragma unroll
            for (int nt = 0; nt < 2; nt++)
                acc[mt][nt] = __builtin_amdgcn_mfma_f32_16x16x32_bf16(af[mt], bf[nt], acc[mt][nt], 0, 0, 0);
    }

    float b2[2];
#pragma unroll
    for (int nt = 0; nt < 2; nt++) b2[nt] = bias[colBase + wc + nt * 16 + col];
#pragma unroll
    for (int mt = 0; mt < 2; mt++) {
#pragma unroll
        for (int r = 0; r < 4; r++) {
            int m = rowBase + wr + mt * 16 + quad * 4 + r;
            float* dst = out + (size_t)m * D_ + colBase + wc;
#pragma unroll
            for (int nt = 0; nt < 2; nt++)
                dst[nt * 16 + col] = acc[mt][nt][r] + b2[nt];
        }
    }
}

// ---------------------------------------------------------------------------
extern "C" void kernel_launch(void* const* d_in, const int* in_sizes, int n_in,
                              void* d_out, int out_size, void* d_ws, size_t ws_size,
                              hipStream_t stream) {
    const float* x    = (const float*)d_in[0];
    const float* Wqkv = (const float*)d_in[1];
    const float* qs   = (const float*)d_in[2];
    const float* qb   = (const float*)d_in[3];
    const float* ks   = (const float*)d_in[4];
    const float* kb   = (const float*)d_in[5];
    const float* osc  = (const float*)d_in[6];
    const float* ob   = (const float*)d_in[7];
    const float* Wout = (const float*)d_in[8];
    const float* bout = (const float*)d_in[9];
    float* out = (float*)d_out;

    // Workspace: qkv bf16 18.9MB | (nsp-1) fp32 O-partials | nsp l-partials.
    // Last partial lives in d_out (fp32, exactly B*P*D elements).
    ushort* qkv = (ushort*)d_ws;
    const size_t qkvE = (size_t)3 * B_ * H_ * P_ * HD_;   // elements
    const size_t oE   = (size_t)B_ * H_ * P_ * HD_;       // fp32 elements
    const size_t lE   = (size_t)B_ * H_ * P_;
    float* base = (float*)(qkv + qkvE);
    const size_t need4 = qkvE * sizeof(ushort) + (3 * oE + 4 * lE) * sizeof(float);
    const int nsp = (ws_size >= need4) ? 4 : 2;
    float* op[4];
    float* lbase;
    if (nsp == 4) {
        op[0] = base; op[1] = base + oE; op[2] = base + 2 * oE; op[3] = out;
        lbase = base + 3 * oE;
    } else {
        op[0] = base; op[1] = out; op[2] = base; op[3] = base;
        lbase = base + oE;
    }
    float* lp[4] = {lbase, lbase + lE, lbase + 2 * lE, lbase + 3 * lE};
    ushort* ln_buf = qkv;   // overlays dead q-region after attention

    gemm_qkv_mfma<<<dim3(N1_ / 128, M_ / 128), 512, 0, stream>>>(x, Wqkv, qs, qb, ks, kb, qkv);
    attn_split<<<dim3(P_ / 128, B_ * H_, nsp), 256, 0, stream>>>(
        qkv, op[0], op[1], op[2], op[3], lp[0], lp[1], lp[2], lp[3]);
    ln_o<<<dim3(M_), 256, 0, stream>>>(
        op[0], op[1], op[2], op[3], lp[0], lp[1], lp[2], lp[3], nsp, ln_buf, osc, ob);
    gemm_out_mfma<<<dim3(D_ / 64, M_ / 64), 256, 0, stream>>>(ln_buf, Wout, bout, out);
}

// Round 7
// 199.284 us; speedup vs baseline: 1.0766x; 1.0111x over previous
//
#include <hip/hip_runtime.h>
#include <hip/hip_bf16.h>

// Problem constants (B=2, P=2048, D=768, H=12, hd=64)
#define B_  2
#define P_  2048
#define D_  768
#define H_  12
#define HD_ 64
#define M_  (B_ * P_)   // 4096
#define N1_ (3 * D_)    // 2304

typedef __attribute__((ext_vector_type(8))) short short8;    // 8 bf16 (4 VGPRs)
typedef __attribute__((ext_vector_type(4))) float f32x4;     // 16x16 MFMA acc
typedef __attribute__((ext_vector_type(16))) float f32x16;   // 32x32 MFMA acc
typedef __attribute__((ext_vector_type(4))) unsigned u32x4;
typedef unsigned short ushort;

__device__ __forceinline__ ushort f2bf(float f) {
    unsigned u = __float_as_uint(f);
    u += 0x7fffu + ((u >> 16) & 1u);   // RNE
    return (ushort)(u >> 16);
}

// Pack 2 floats -> 1 dword of 2x bf16 (lo=a, hi=b), RNE. HW-verified (r5/r6).
__device__ __forceinline__ unsigned cvtpk(float a, float b) {
    unsigned r;
    asm("v_cvt_pk_bf16_f32 %0, %1, %2" : "=v"(r) : "v"(a), "v"(b));
    return r;
}

// Swap bits 2 and 3 of a slot index (involution). Staging K rows at slot
// swap23(kr) makes the 32x32 MFMA C-layout's half-interleaved row order come
// out as the exact PV B-fragment element order — no cross-lane exchange.
__device__ __forceinline__ int swap23(int s) {
    return (s & ~12) | ((s & 4) << 1) | ((s & 8) >> 1);
}

// Q pre-scale: hd^-0.5 * log2(e) — attn uses exp2 directly (v_exp_f32 is 2^x).
#define QSC_ (0.125f * 1.44269504088896340736f)

// ===========================================================================
// Kernel 1: qkv = x @ W_qkv (bf16 MFMA) + fused per-head QK-LayerNorm.
// 128x128 tile, BK=32, 512 threads / 8 waves (4x2). (unchanged from R6)
// ===========================================================================
__global__ __launch_bounds__(512) void gemm_qkv_mfma(
        const float* __restrict__ x, const float* __restrict__ w,
        const float* __restrict__ qs, const float* __restrict__ qb,
        const float* __restrict__ ks, const float* __restrict__ kb,
        ushort* __restrict__ qkv) {
    __shared__ __align__(16) ushort As[128][40];
    __shared__ __align__(16) ushort Bs[128][40];

    const int tid  = threadIdx.x;
    const int lane = tid & 63;
    const int wv   = tid >> 6;            // 0..7
    const int quad = lane >> 4;
    const int col  = lane & 15;
    const int wr   = (wv >> 1) * 32;
    const int wc   = (wv & 1) * 64;
    const int rowBase = blockIdx.y * 128;
    const int colBase = blockIdx.x * 128;

    const int am0 = tid >> 3, ac4 = tid & 7;
    const int nB  = tid & 127, kq = tid >> 7;

    float4 apre[2];
    float  bpre[8];
    auto load_tile = [&](int kt) {
        const int k0 = kt * 32;
        apre[0] = *(const float4*)(x + (size_t)(rowBase + am0) * D_ + k0 + ac4 * 4);
        apre[1] = *(const float4*)(x + (size_t)(rowBase + am0 + 64) * D_ + k0 + ac4 * 4);
#pragma unroll
        for (int j = 0; j < 8; j++)
            bpre[j] = w[(size_t)(k0 + kq * 8 + j) * N1_ + colBase + nB];
    };

    f32x4 acc[2][4];
#pragma unroll
    for (int i = 0; i < 2; i++)
#pragma unroll
        for (int j = 0; j < 4; j++) acc[i][j] = (f32x4){0.f, 0.f, 0.f, 0.f};

    load_tile(0);
    const int NT = D_ / 32;
    for (int kt = 0; kt < NT; kt++) {
        __syncthreads();
        {
            uint2 a0 = {cvtpk(apre[0].x, apre[0].y), cvtpk(apre[0].z, apre[0].w)};
            uint2 a1 = {cvtpk(apre[1].x, apre[1].y), cvtpk(apre[1].z, apre[1].w)};
            *(uint2*)&As[am0][ac4 * 4]      = a0;
            *(uint2*)&As[am0 + 64][ac4 * 4] = a1;
            u32x4 bb;
#pragma unroll
            for (int j = 0; j < 4; j++) bb[j] = cvtpk(bpre[2 * j], bpre[2 * j + 1]);
            *(u32x4*)&Bs[nB][kq * 8] = bb;
        }
        __syncthreads();
        if (kt + 1 < NT) load_tile(kt + 1);

        short8 af[2], bf[4];
#pragma unroll
        for (int mt = 0; mt < 2; mt++) af[mt] = *(const short8*)&As[wr + mt * 16 + col][quad * 8];
#pragma unroll
        for (int nt = 0; nt < 4; nt++) bf[nt] = *(const short8*)&Bs[wc + nt * 16 + col][quad * 8];
#pragma unroll
        for (int mt = 0; mt < 2; mt++)
#pragma unroll
            for (int nt = 0; nt < 4; nt++)
                acc[mt][nt] = __builtin_amdgcn_mfma_f32_16x16x32_bf16(af[mt], bf[nt], acc[mt][nt], 0, 0, 0);
    }

    const int comp = colBase / D_;
    const int rem  = colBase + wc - comp * D_;
    const int h    = rem >> 6;
    float sc4[4] = {0, 0, 0, 0}, bi4[4] = {0, 0, 0, 0};
    if (comp == 0) {
#pragma unroll
        for (int nt = 0; nt < 4; nt++) { sc4[nt] = qs[nt * 16 + col]; bi4[nt] = qb[nt * 16 + col]; }
    } else if (comp == 1) {
#pragma unroll
        for (int nt = 0; nt < 4; nt++) { sc4[nt] = ks[nt * 16 + col]; bi4[nt] = kb[nt * 16 + col]; }
    }

#pragma unroll
    for (int mt = 0; mt < 2; mt++) {
#pragma unroll
        for (int r = 0; r < 4; r++) {
            int m  = rowBase + wr + mt * 16 + quad * 4 + r;
            int bb = m >> 11;
            int p  = m & 2047;
            float v0 = acc[mt][0][r], v1 = acc[mt][1][r], v2 = acc[mt][2][r], v3 = acc[mt][3][r];
            if (comp < 2) {
                float s = v0 + v1 + v2 + v3;
#pragma unroll
                for (int off = 1; off < 16; off <<= 1) s += __shfl_xor(s, off, 64);
                float mean = s * (1.0f / 64.0f);
                float d0 = v0 - mean, d1 = v1 - mean, d2 = v2 - mean, d3 = v3 - mean;
                float sq = d0 * d0 + d1 * d1 + d2 * d2 + d3 * d3;
#pragma unroll
                for (int off = 1; off < 16; off <<= 1) sq += __shfl_xor(sq, off, 64);
                float inv = rsqrtf(sq * (1.0f / 64.0f) + 1e-6f);
                v0 = d0 * inv * sc4[0] + bi4[0];
                v1 = d1 * inv * sc4[1] + bi4[1];
                v2 = d2 * inv * sc4[2] + bi4[2];
                v3 = d3 * inv * sc4[3] + bi4[3];
                if (comp == 0) { v0 *= QSC_; v1 *= QSC_; v2 *= QSC_; v3 *= QSC_; }
            }
            size_t base = ((((size_t)comp * B_ + bb) * H_ + h) * P_ + p) * HD_;
            qkv[base +  0 + col] = f2bf(v0);
            qkv[base + 16 + col] = f2bf(v1);
            qkv[base + 32 + col] = f2bf(v2);
            qkv[base + 48 + col] = f2bf(v3);
        }
    }
}

// ===========================================================================
// Kernel 2: flash attention, swapped-operand QK^T; P^T PV-fragments built
// in-register via the K-slot swap23 staging permutation (verified R3-R6).
// NEW (R7): double-buffered K/V LDS — ONE barrier per 64-key tile. The
// end-of-iteration barrier guarantees all waves finished reading buf^1
// (iteration kt-1) before any wave writes it in iteration kt. Clamp dropped:
// post-LN |q|2 = 8*QSC, |k|2 = 8 => |S| <= 11.5, far from exp2 overflow.
// PV issues per 32-key block right after its pack (halves live pw regs).
// Epilogue scratch = buffer 0; last tile (NT-1 odd => cur=1) reads buffer 1,
// and the kt=NT-2 barrier ordered all buffer-0 reads before it — no overlap.
// ===========================================================================
__global__ __launch_bounds__(256) void attn_split(const ushort* __restrict__ qkv,
                                                  float* __restrict__ o0, float* __restrict__ o1,
                                                  float* __restrict__ o2, float* __restrict__ o3,
                                                  float* __restrict__ l0, float* __restrict__ l1,
                                                  float* __restrict__ l2, float* __restrict__ l3) {
    const int p0  = blockIdx.x * 128;
    const int bh  = blockIdx.y;
    const int s   = blockIdx.z;
    const int nsp = gridDim.z;           // 2 or 4
    const int b   = bh / H_, h = bh % H_;
    float* opart = (s == 0) ? o0 : (s == 1) ? o1 : (s == 2) ? o2 : o3;
    float* lpart = (s == 0) ? l0 : (s == 1) ? l1 : (s == 2) ? l2 : l3;
    const int tid  = threadIdx.x;
    const int lane = tid & 63;
    const int wv   = tid >> 6;
    const int half = lane >> 5;     // 0/1
    const int n32  = lane & 31;     // q-column of this lane

    // [buf][K=0/V=1][row][col]; K: [key SLOT][dim] (slot=swap23), V: [dim][key]
    __shared__ __align__(16) ushort KVs[2][2][64][72];

    const size_t hs  = (size_t)P_ * HD_;
    const int    kv0 = s * (P_ / nsp);
    const ushort* qg = qkv + ((size_t)(0 * B_ + b) * H_ + h) * hs + (size_t)(p0 + wv * 32) * HD_;
    const ushort* kg = qkv + ((size_t)(1 * B_ + b) * H_ + h) * hs + (size_t)kv0 * HD_;
    const ushort* vg = qkv + ((size_t)(2 * B_ + b) * H_ + h) * hs + (size_t)kv0 * HD_;

    // Q fragments (B-operand of swapped QK): B[k=8*half+j][n=q=n32].
    short8 aq[4];
#pragma unroll
    for (int ks2 = 0; ks2 < 4; ks2++)
        aq[ks2] = *(const short8*)(qg + (size_t)n32 * HD_ + ks2 * 16 + half * 8);

    float lsum = 0.f;
    f32x16 oaccT[2];
#pragma unroll
    for (int nt = 0; nt < 2; nt++)
#pragma unroll
        for (int r = 0; r < 16; r++) oaccT[nt][r] = 0.f;

    const int kr = tid >> 3, kc8 = tid & 7;
    const int krs = swap23(kr);          // K staging slot (swap23(kr+32)=krs+32)
    const int vd = tid & 63,  vkh = tid >> 6;

    uint4  kpre[2];
    ushort vpre[16];
    auto load_tile = [&](int kt) {
        const ushort* kg_t = kg + (size_t)kt * 64 * HD_;
        const ushort* vg_t = vg + (size_t)kt * 64 * HD_;
        kpre[0] = *(const uint4*)(kg_t + (size_t)kr * HD_ + kc8 * 8);
        kpre[1] = *(const uint4*)(kg_t + (size_t)(kr + 32) * HD_ + kc8 * 8);
#pragma unroll
        for (int j = 0; j < 16; j++)
            vpre[j] = vg_t[(size_t)(vkh * 16 + j) * HD_ + vd];
    };
    auto stage = [&](int buf) {
        *(uint4*)&KVs[buf][0][krs][kc8 * 8]      = kpre[0];
        *(uint4*)&KVs[buf][0][krs + 32][kc8 * 8] = kpre[1];
        *(short8*)&KVs[buf][1][vd][vkh * 16]     = *(short8*)&vpre[0];
        *(short8*)&KVs[buf][1][vd][vkh * 16 + 8] = *(short8*)&vpre[8];
    };

    load_tile(0);
    stage(0);
    __syncthreads();

    const int NT = (P_ / 64) / nsp;    // 8 (nsp=4) or 16 (nsp=2) — even
    int cur = 0;
    for (int kt = 0; kt < NT; kt++) {
        const bool more = (kt + 1 < NT);
        if (more) load_tile(kt + 1);

        ushort (*Ks)[72] = KVs[cur][0];
        ushort (*Vs)[72] = KVs[cur][1];

#pragma unroll
        for (int nt = 0; nt < 2; nt++) {
            f32x16 sc;
#pragma unroll
            for (int r = 0; r < 16; r++) sc[r] = 0.f;
#pragma unroll
            for (int ks2 = 0; ks2 < 4; ks2++) {
                short8 kb2 = *(const short8*)&Ks[nt * 32 + n32][ks2 * 16 + half * 8];
                sc = __builtin_amdgcn_mfma_f32_32x32x16_bf16(kb2, aq[ks2], sc, 0, 0, 0);
            }
            float p[16];
#pragma unroll
            for (int r = 0; r < 16; r++) {
                p[r] = __builtin_amdgcn_exp2f(sc[r]);
                lsum += p[r];
            }
            unsigned w[8];
#pragma unroll
            for (int i = 0; i < 8; i++) w[i] = cvtpk(p[2 * i], p[2 * i + 1]);
            // PV for this 32-key block: kstep = nt*2 + kp2.
#pragma unroll
            for (int kp2 = 0; kp2 < 2; kp2++) {
                u32x4 t = {w[kp2 * 4 + 0], w[kp2 * 4 + 1], w[kp2 * 4 + 2], w[kp2 * 4 + 3]};
                short8 pb = __builtin_bit_cast(short8, t);
                const int kstep = nt * 2 + kp2;
#pragma unroll
                for (int ntd = 0; ntd < 2; ntd++) {
                    short8 av = *(const short8*)&Vs[ntd * 32 + n32][kstep * 16 + half * 8];
                    oaccT[ntd] = __builtin_amdgcn_mfma_f32_32x32x16_bf16(av, pb, oaccT[ntd], 0, 0, 0);
                }
            }
        }

        if (more) {
            stage(cur ^ 1);
            __syncthreads();
            cur ^= 1;
        }
    }

    // Row-sum: lane-local accumulation + one cross-half exchange.
    lsum += __shfl_xor(lsum, 32, 64);
    if (lane < 32)
        lpart[(size_t)bh * P_ + p0 + wv * 32 + lane] = lsum;

    // O^T -> O transpose through buffer-0 LDS (per-wave 32x36 f32 scratch).
    // Last tile read buffer 1 (NT even => cur=1); buffer 0's reads were
    // ordered by the kt=NT-2 barrier. In-wave DS ordering covers write->read.
    float* scr = (float*)&KVs[0][0][0][0] + wv * 1152;
#pragma unroll
    for (int ntd = 0; ntd < 2; ntd++) {
#pragma unroll
        for (int r = 0; r < 16; r++)
            scr[n32 * 36 + (r & 3) + 8 * (r >> 2) + 4 * half] = oaccT[ntd][r];
#pragma unroll
        for (int i = 0; i < 4; i++) {
            int ql = i * 8 + (lane >> 3);
            int c4 = lane & 7;
            float4 v = *(const float4*)&scr[ql * 36 + c4 * 4];
            *(float4*)(opart + ((size_t)bh * P_ + p0 + wv * 32 + ql) * HD_ + ntd * 32 + c4 * 4) = v;
        }
    }
}

// ===========================================================================
// Kernel 3: LayerNorm over D=768, fused split-combine (2- or 4-way):
// v = (sum_s o_s) / (sum_s l_s). Sole owner of normalization. (unchanged)
// ===========================================================================
__global__ __launch_bounds__(256) void ln_o(const float* __restrict__ o0,
                                            const float* __restrict__ o1,
                                            const float* __restrict__ o2,
                                            const float* __restrict__ o3,
                                            const float* __restrict__ l0,
                                            const float* __restrict__ l1,
                                            const float* __restrict__ l2,
                                            const float* __restrict__ l3,
                                            const int ns,
                                            ushort* __restrict__ lnb,
                                            const float* __restrict__ osc,
                                            const float* __restrict__ ob) {
    __shared__ float red[4];
    __shared__ float red2[4];
    const int row = blockIdx.x;          // b*P + p
    const int b   = row >> 11;
    const int p   = row & (P_ - 1);
    const int tid = threadIdx.x;

    auto src = [&](int d) {
        int h = d >> 6;
        size_t lr  = (size_t)(b * H_ + h) * P_ + p;
        size_t idx = lr * HD_ + (d & 63);
        float num = o0[idx] + o1[idx];
        float den = l0[lr] + l1[lr];
        if (ns == 4) { num += o2[idx] + o3[idx]; den += l2[lr] + l3[lr]; }
        return num / den;
    };
    float v0 = src(tid);
    float v1 = src(tid + 256);
    float v2 = src(tid + 512);
    float s = v0 + v1 + v2;
#pragma unroll
    for (int o = 32; o > 0; o >>= 1) s += __shfl_xor(s, o, 64);
    if ((tid & 63) == 0) red[tid >> 6] = s;
    __syncthreads();
    float mean = (red[0] + red[1] + red[2] + red[3]) * (1.0f / 768.0f);
    float d0 = v0 - mean, d1 = v1 - mean, d2 = v2 - mean;
    float sq = d0 * d0 + d1 * d1 + d2 * d2;
#pragma unroll
    for (int o = 32; o > 0; o >>= 1) sq += __shfl_xor(sq, o, 64);
    if ((tid & 63) == 0) red2[tid >> 6] = sq;
    __syncthreads();
    float var = (red2[0] + red2[1] + red2[2] + red2[3]) * (1.0f / 768.0f);
    float inv = rsqrtf(var + 1e-6f);
    const size_t base = (size_t)row * D_;
    lnb[base + tid]       = f2bf(d0 * inv * osc[tid]       + ob[tid]);
    lnb[base + tid + 256] = f2bf(d1 * inv * osc[tid + 256] + ob[tid + 256]);
    lnb[base + tid + 512] = f2bf(d2 * inv * osc[tid + 512] + ob[tid + 512]);
}

// ===========================================================================
// Kernel 4: out = ln_buf(bf16) @ W_out + b_out. 64x64 tile. (unchanged)
// ===========================================================================
__global__ __launch_bounds__(256) void gemm_out_mfma(
        const ushort* __restrict__ a, const float* __restrict__ w,
        const float* __restrict__ bias, float* __restrict__ out) {
    __shared__ __align__(16) ushort As[64][40];
    __shared__ __align__(16) ushort Bs[64][40];

    const int tid  = threadIdx.x;
    const int lane = tid & 63;
    const int wv   = tid >> 6;
    const int quad = lane >> 4;
    const int col  = lane & 15;
    const int wr   = (wv >> 1) * 32;
    const int wc   = (wv & 1) * 32;
    const int rowBase = blockIdx.y * 64;
    const int colBase = blockIdx.x * 64;

    const int am  = tid >> 2, ac8 = tid & 3;
    const int nB  = tid & 63, kq = tid >> 6;

    uint4 apre;
    float bpre[8];
    auto load_tile = [&](int kt) {
        const int k0 = kt * 32;
        apre = *(const uint4*)(a + (size_t)(rowBase + am) * D_ + k0 + ac8 * 8);
#pragma unroll
        for (int j = 0; j < 8; j++)
            bpre[j] = w[(size_t)(k0 + kq * 8 + j) * D_ + colBase + nB];
    };

    f32x4 acc[2][2];
#pragma unroll
    for (int i = 0; i < 2; i++)
#pragma unroll
        for (int j = 0; j < 2; j++) acc[i][j] = (f32x4){0.f, 0.f, 0.f, 0.f};

    load_tile(0);
    const int NT = D_ / 32;
    for (int kt = 0; kt < NT; kt++) {
        __syncthreads();
        *(uint4*)&As[am][ac8 * 8] = apre;
        {
            u32x4 bb;
#pragma unroll
            for (int j = 0; j < 4; j++) bb[j] = cvtpk(bpre[2 * j], bpre[2 * j + 1]);
            *(u32x4*)&Bs[nB][kq * 8] = bb;
        }
        __syncthreads();
        if (kt + 1 < NT) load_tile(kt + 1);

        short8 af[2], bf[2];
#pragma unroll
        for (int mt = 0; mt < 2; mt++) af[mt] = *(const short8*)&As[wr + mt * 16 + col][quad * 8];
#pragma unroll
        for (int nt = 0; nt < 2; nt++) bf[nt] = *(const short8*)&Bs[wc + nt * 16 + col][quad * 8];
#pragma unroll
        for (int mt = 0; mt < 2; mt++)
#pragma unroll
            for (int nt = 0; nt < 2; nt++)
                acc[mt][nt] = __builtin_amdgcn_mfma_f32_16x16x32_bf16(af[mt], bf[nt], acc[mt][nt], 0, 0, 0);
    }

    float b2[2];
#pragma unroll
    for (int nt = 0; nt < 2; nt++) b2[nt] = bias[colBase + wc + nt * 16 + col];
#pragma unroll
    for (int mt = 0; mt < 2; mt++) {
#pragma unroll
        for (int r = 0; r < 4; r++) {
            int m = rowBase + wr + mt * 16 + quad * 4 + r;
            float* dst = out + (size_t)m * D_ + colBase + wc;
#pragma unroll
            for (int nt = 0; nt < 2; nt++)
                dst[nt * 16 + col] = acc[mt][nt][r] + b2[nt];
        }
    }
}

// ---------------------------------------------------------------------------
extern "C" void kernel_launch(void* const* d_in, const int* in_sizes, int n_in,
                              void* d_out, int out_size, void* d_ws, size_t ws_size,
                              hipStream_t stream) {
    const float* x    = (const float*)d_in[0];
    const float* Wqkv = (const float*)d_in[1];
    const float* qs   = (const float*)d_in[2];
    const float* qb   = (const float*)d_in[3];
    const float* ks   = (const float*)d_in[4];
    const float* kb   = (const float*)d_in[5];
    const float* osc  = (const float*)d_in[6];
    const float* ob   = (const float*)d_in[7];
    const float* Wout = (const float*)d_in[8];
    const float* bout = (const float*)d_in[9];
    float* out = (float*)d_out;

    // Workspace: qkv bf16 18.9MB | (nsp-1) fp32 O-partials | nsp l-partials.
    // Last partial lives in d_out (fp32, exactly B*P*D elements).
    ushort* qkv = (ushort*)d_ws;
    const size_t qkvE = (size_t)3 * B_ * H_ * P_ * HD_;   // elements
    const size_t oE   = (size_t)B_ * H_ * P_ * HD_;       // fp32 elements
    const size_t lE   = (size_t)B_ * H_ * P_;
    float* base = (float*)(qkv + qkvE);
    const size_t need4 = qkvE * sizeof(ushort) + (3 * oE + 4 * lE) * sizeof(float);
    const int nsp = (ws_size >= need4) ? 4 : 2;
    float* op[4];
    float* lbase;
    if (nsp == 4) {
        op[0] = base; op[1] = base + oE; op[2] = base + 2 * oE; op[3] = out;
        lbase = base + 3 * oE;
    } else {
        op[0] = base; op[1] = out; op[2] = base; op[3] = base;
        lbase = base + oE;
    }
    float* lp[4] = {lbase, lbase + lE, lbase + 2 * lE, lbase + 3 * lE};
    ushort* ln_buf = qkv;   // overlays dead q-region after attention

    gemm_qkv_mfma<<<dim3(N1_ / 128, M_ / 128), 512, 0, stream>>>(x, Wqkv, qs, qb, ks, kb, qkv);
    attn_split<<<dim3(P_ / 128, B_ * H_, nsp), 256, 0, stream>>>(
        qkv, op[0], op[1], op[2], op[3], lp[0], lp[1], lp[2], lp[3]);
    ln_o<<<dim3(M_), 256, 0, stream>>>(
        op[0], op[1], op[2], op[3], lp[0], lp[1], lp[2], lp[3], nsp, ln_buf, osc, ob);
    gemm_out_mfma<<<dim3(D_ / 64, M_ / 64), 256, 0, stream>>>(ln_buf, Wout, bout, out);
}